// Round 12
// baseline (496.207 us; speedup 1.0000x reference)
//
#include <hip/hip_runtime.h>

#define NR 4096
#define NT 96
#define NNZ_CAP 10240
#define SREM_CAP 4096
#define LONG_CAP 4096
#define WLDS 8
#define SSTR 4112      // win slot stride (elements): 4096 cols + pad cell @4096
#define SHORTLAG 7     // lag <= 7 via LDS window
#define DHIST 32       // Qhist depth; safe for lag <= 31 (fallback beyond)
#define DTSTEP 3600.0f
#define LOG2_1E6 -19.931568f

__device__ __forceinline__ float RCP(float x) { return __builtin_amdgcn_rcpf(x); }
__device__ __forceinline__ float EXP2(float x) { return __builtin_amdgcn_exp2f(x); }
__device__ __forceinline__ float LOG2(float x) { return __builtin_amdgcn_logf(x); }

// Phase barrier: retire LDS ops (win visibility), bound VMEM at 12, sync.
// Qhist stores are read >=8 phases later; a wave issues >=4 new VMEM ops per
// phase, so vmcnt(12) retires any store within ~3 phases. lat prefetches are
// covered by the compiler's waitcnt before their first use.
__device__ __forceinline__ void phase_barrier() {
  asm volatile("s_waitcnt lgkmcnt(0) vmcnt(12)" ::: "memory");
  __builtin_amdgcn_s_barrier();
  asm volatile("" ::: "memory");
}

// ---------- K1: dense int mask -> CSR (old ids), SINGLE HBM pass ----------
__global__ void mc_build(const int* __restrict__ mask, int* __restrict__ rowBase,
                         int* __restrict__ rowCnt, int* __restrict__ gctr,
                         unsigned short* __restrict__ cols) {
  __shared__ unsigned short tmp[80];
  __shared__ int baseS;
  int row = blockIdx.x;
  int lane = threadIdx.x;
  const int* rs = mask + (size_t)row * NR;
  int total = 0;
  for (int j0 = 0; j0 < NR; j0 += 64) {
    int j = j0 + lane;
    int pred = (rs[j] != 0);
    unsigned long long m = __ballot(pred);
    if (pred) {
      int pos = total + __popcll(m & ((1ull << lane) - 1ull));
      if (pos < 80) tmp[pos] = (unsigned short)j;
    }
    total += __popcll(m);
  }
  if (total > 80) total = 80;
  if (lane == 0) {
    int b = atomicAdd(gctr, total);
    rowBase[row] = b;
    rowCnt[row] = total;
    baseS = b;
  }
  __syncthreads();
  int base = baseS;
  for (int e = lane; e < total; e += 64) {
    int p = base + e;
    if (p < NNZ_CAP) cols[p] = tmp[e];
  }
}

// ---------- K2: FUSED prep + route, single workgroup ----------
// Prep scratch overlays the win_s region (disjoint from all later reads of
// that region: every win cell consumed in the main loop is written in an
// earlier phase of the same timestep; only the 8 pad cells need zeroing,
// done AFTER the scratch->register loads since pads alias scratch).
__global__ __launch_bounds__(1024, 4) void mc_fused(
    const float* __restrict__ lat, const float* __restrict__ initQ,
    const float* __restrict__ Lg, const float* __restrict__ Sg,
    const float* __restrict__ mng, const float* __restrict__ wcg,
    const float* __restrict__ weg, const float* __restrict__ dcg,
    const float* __restrict__ deg, const int* __restrict__ rowBase,
    const int* __restrict__ rowCnt, const int* __restrict__ gctr,
    const unsigned short* __restrict__ colsOld, float* Qhist,
    float* __restrict__ out) {
  __shared__ float win_s[WLDS * SSTR];        // 131584 B
  __shared__ unsigned short srem_s[SREM_CAP]; // 8192 B
  __shared__ unsigned short long_s[LONG_CAP]; // 8192 B
  __shared__ int ws16[16];
  __shared__ int flagA[40];
  __shared__ int maxLevS, sremCur, longCur, outletS;

  // prep scratch overlay inside win_s (byte offsets; all disjoint)
  char* base = (char*)win_s;
  unsigned short* cols_s = (unsigned short*)(base);            // 0..20479
  unsigned char* lev_s = (unsigned char*)(base + 20480);       // ..24575
  unsigned char* lsrc_s = (unsigned char*)(base + 24576);      // ..28671
  unsigned short* newid_s = (unsigned short*)(base + 28672);   // ..36863
  unsigned short* order_s = (unsigned short*)(base + 36864);   // ..45055
  int* cnt = (int*)(base + 45056);                             // ..49151
  unsigned short* scolT = (unsigned short*)(base + 49152);     // ..81919
  unsigned int* smetaT = (unsigned int*)(base + 81920);        // ..98303
  unsigned int* lmetaT = (unsigned int*)(base + 98304);        // ..114687
  unsigned short* levT = (unsigned short*)(base + 114688);     // ..122879
  unsigned short* oldiT = (unsigned short*)(base + 122880);    // ..131071

  const int tid = threadIdx.x;
  int nnz = gctr[0];
  if (nnz > NNZ_CAP) nnz = NNZ_CAP;
  for (int e = tid; e < nnz; e += 1024) cols_s[e] = colsOld[e];
  for (int i = tid; i < 40; i += 1024) flagA[i] = 0;
  if (tid == 0) {
    maxLevS = 0;
    sremCur = 0;
    longCur = 0;
    outletS = 0;
  }

  int pb_r[4], pe_r[4];
#pragma unroll
  for (int k = 0; k < 4; ++k) {
    int i = 4 * tid + k;
    int b = rowBase[i];
    if (b > NNZ_CAP) b = NNZ_CAP;
    int e = b + rowCnt[i];
    if (e > NNZ_CAP) e = NNZ_CAP;
    pb_r[k] = b;
    pe_r[k] = e;
    lev_s[i] = 0;
    lsrc_s[i] = 0;
  }
  __syncthreads();

  // longest-path level relaxation, 1 barrier/pass (monotone; benign races)
  for (int pass = 0; pass < 34; ++pass) {
    int ch = 0;
#pragma unroll
    for (int k = 0; k < 4; ++k) {
      int i = 4 * tid + k;
      int lv = 0;
      for (int e = pb_r[k]; e < pe_r[k]; ++e) {
        int l2 = (int)lev_s[cols_s[e]] + 1;
        lv = lv > l2 ? lv : l2;
      }
      if (lv > 60) lv = 60;
      if (lv > (int)lev_s[i]) {
        lev_s[i] = (unsigned char)lv;
        ch = 1;
      }
    }
    if (ch) flagA[pass] = 1;  // benign race, all write 1
    __syncthreads();
    if (flagA[pass] == 0) break;
  }
  {
    int lm = 0;
#pragma unroll
    for (int k = 0; k < 4; ++k) {
      int l = lev_s[4 * tid + k];
      lm = lm > l ? lm : l;
    }
    atomicMax(&maxLevS, lm);
  }
  __syncthreads();
  const int maxLev = maxLevS;
  const int nlv = maxLev + 1;

  if (maxLev >= 32) {
    // safety fallback (statistically impossible): per-t level sweep using
    // cols_s (already loaded) + Qhist; identity order.
    int b_r[4], e_r[4], lev_r[4];
    float lwc_r[4], we_r[4], ldc_r[4], de_r[4], lvk_r[4], SL_r[4], L_r[4];
    float ip_r[4], q1_r[4], q2_r[4];
#pragma unroll
    for (int k = 0; k < 4; ++k) {
      int i = tid + k * 1024;
      lev_r[k] = (int)lev_s[i];
      int b = rowBase[i];
      if (b > NNZ_CAP) b = NNZ_CAP;
      int e = b + rowCnt[i];
      if (e > NNZ_CAP) e = NNZ_CAP;
      b_r[k] = b;
      e_r[k] = e;
      float Lv = Lg[i];
      float sS = fmaxf(Sg[i], 1e-6f);
      float mnv = fmaxf(mng[i], 1e-3f);
      lvk_r[k] = 0.7369656f + 0.5f * LOG2(sS) - LOG2(mnv);
      SL_r[k] = sS * Lv;
      L_r[k] = Lv;
      lwc_r[k] = LOG2(wcg[i]);
      we_r[k] = weg[i];
      ldc_r[k] = LOG2(dcg[i]);
      de_r[k] = deg[i];
      float q0 = initQ[i];
      q1_r[k] = q0;
      q2_r[k] = q0;
      ip_r[k] = 0.f;
    }
    __syncthreads();
    for (int t = 0; t < NT; ++t) {
      for (int l = 0; l < nlv; ++l) {
#pragma unroll
        for (int k = 0; k < 4; ++k) {
          if (lev_r[k] == l) {
            int i = tid + k * 1024;
            float latv = lat[t * NR + i];
            float Qref = fmaxf(q1_r[k], 0.1f);
            float lq = LOG2(Qref);
            float lgW = fmaf(we_r[k], lq, lwc_r[k]);
            float W = EXP2(lgW);
            float aD = fmaf(de_r[k], lq, ldc_r[k]);
            float Dd = EXP2(aD);
            float lgR = fmaxf(lgW + aD - LOG2(fmaf(2.f, Dd, W)), LOG2_1E6);
            float c = fmaxf(EXP2(fmaf(0.66666667f, lgR, lvk_r[k])), 0.01f);
            float K = fmaxf(L_r[k] * RCP(c), 360.f);
            float X =
                fmaxf(0.5f - 0.5f * Qref * RCP(fmaf(W * c, SL_r[k], 1e-6f)), 0.f);
            float twoKX = 2.f * K * X;
            float C0 = fmaxf(DTSTEP - twoKX, 0.f);
            float C1 = DTSTEP + twoKX;
            float C2 = fmaxf(2.f * K - twoKX - DTSTEP, 0.f);
            float inv = RCP(C0 + C1 + C2);
            float sup = 0.f;
            for (int e = b_r[k]; e < e_r[k]; ++e) sup += Qhist[cols_s[e]];
            float Icurr = sup + latv;
            float Qout =
                fmaxf((C0 * Icurr + C1 * ip_r[k] + C2 * q2_r[k]) * inv, 0.f);
            Qhist[i] = Qout;
            ip_r[k] = Icurr;
            q2_r[k] = q1_r[k];
            q1_r[k] = Qout;
            if (i == NR - 1) out[t] = Qout;
          }
        }
        __syncthreads();
      }
    }
    return;
  }

  // counting sort by bucket = lev*32 + min(deg,31)
  cnt[tid] = 0;
  __syncthreads();
  int bkt_r[4];
#pragma unroll
  for (int k = 0; k < 4; ++k) {
    int i = 4 * tid + k;
    int d = pe_r[k] - pb_r[k];
    if (d > 31) d = 31;
    int bkt = ((int)lev_s[i]) * 32 + d;
    bkt_r[k] = bkt;
    atomicAdd(&cnt[bkt], 1);
  }
  __syncthreads();
  {  // exclusive scan of cnt via wave shuffles (2 barriers)
    int v = cnt[tid];
    int lane = tid & 63, wid = tid >> 6;
    int x = v;
#pragma unroll
    for (int off = 1; off < 64; off <<= 1) {
      int y = __shfl_up(x, off);
      if (lane >= off) x += y;
    }
    if (lane == 63) ws16[wid] = x;
    __syncthreads();
    if (wid == 0) {
      int wv = (lane < 16) ? ws16[lane] : 0;
#pragma unroll
      for (int off = 1; off < 16; off <<= 1) {
        int y = __shfl_up(wv, off);
        if (lane >= off) wv += y;
      }
      if (lane < 16) ws16[lane] = wv;
    }
    __syncthreads();
    int sb = wid ? ws16[wid - 1] : 0;
    cnt[tid] = sb + x - v;  // exclusive prefix -> cursor
  }
  __syncthreads();
#pragma unroll
  for (int k = 0; k < 4; ++k) {
    int i = 4 * tid + k;
    int pos = atomicAdd(&cnt[bkt_r[k]], 1);
    order_s[pos] = (unsigned short)i;
    newid_s[i] = (unsigned short)pos;
  }
  __syncthreads();

  // emission: per new-row p -> scolT (byte offs, pad=16384), srem_s, long_s
#pragma unroll
  for (int k = 0; k < 4; ++k) {
    int p = 4 * tid + k;
    int oldi = order_s[p];
    int lp = (int)lev_s[oldi];
    int b = rowBase[oldi];
    if (b > NNZ_CAP) b = NNZ_CAP;
    int e = b + rowCnt[oldi];
    if (e > NNZ_CAP) e = NNZ_CAP;
    int nS = 0, nR = 0, nL = 0;
    for (int ee = b; ee < e; ++ee) {
      int lag = lp - (int)lev_s[cols_s[ee]];
      if (lag <= SHORTLAG) {
        if (nS < 4) ++nS; else ++nR;
      } else ++nL;
    }
    if (nR > 63) nR = 63;
    if (nL > 63) nL = 63;
    int sB = nR ? atomicAdd(&sremCur, nR) : 0;
    int lB = nL ? atomicAdd(&longCur, nL) : 0;
    if (sB > SREM_CAP) sB = SREM_CAP;
    if (sB + nR > SREM_CAP) nR = SREM_CAP - sB;
    if (lB > LONG_CAP) lB = LONG_CAP;
    if (lB + nL > LONG_CAP) nL = LONG_CAP - lB;
    unsigned short sc[4] = {16384, 16384, 16384, 16384};
    int iS = 0, cR = 0, cL = 0;
    for (int ee = b; ee < e; ++ee) {
      int cOld = cols_s[ee];
      int cN = newid_s[cOld];
      int lag = lp - (int)lev_s[cOld];
      if (lag <= SHORTLAG) {
        if (iS < 4) sc[iS++] = (unsigned short)(cN << 2);
        else if (cR < nR) { srem_s[sB + cR] = (unsigned short)(cN << 2); ++cR; }
      } else {
        if (cL < nL) { long_s[lB + cL] = (unsigned short)(cN << 2); ++cL; }
        lsrc_s[cN] = 1;  // benign race, all write 1
      }
    }
    scolT[4 * p + 0] = sc[0];
    scolT[4 * p + 1] = sc[1];
    scolT[4 * p + 2] = sc[2];
    scolT[4 * p + 3] = sc[3];
    smetaT[p] = (unsigned)sB | ((unsigned)nR << 20);
    lmetaT[p] = (unsigned)lB | ((unsigned)nL << 20);
    levT[p] = (unsigned short)lp;
    oldiT[p] = (unsigned short)oldi;
    if (oldi == NR - 1) outletS = p;
  }
  __syncthreads();

  // scratch -> registers for the route loop (thread owns p = tid + k*1024)
  int sc_r[4][4];
  int lev_r[4], io_r[4], ls_r[4], wOff_r[4];
  unsigned int smeta_r[4], lmeta_r[4];
  const float* latcol_r[4];
  float lwc_r[4], we_r[4], ldc_r[4], de_r[4], lvk_r[4], lgSL_r[4], L_r[4];
  float ip_r[4], q1_r[4], q2_r[4], latN_r[4];
  const int outletNew = outletS;
#pragma unroll
  for (int k = 0; k < 4; ++k) {
    int p = tid + k * 1024;
    int oldi = oldiT[p];
    lev_r[k] = (int)levT[p];
    uint2 cc = *(const uint2*)(scolT + 4 * p);
    sc_r[k][0] = cc.x & 0xFFFFu;  // byte offsets within a win slot
    sc_r[k][1] = cc.x >> 16;
    sc_r[k][2] = cc.y & 0xFFFFu;
    sc_r[k][3] = cc.y >> 16;
    smeta_r[k] = smetaT[p];
    lmeta_r[k] = lmetaT[p];
    ls_r[k] = (int)lsrc_s[p];
    io_r[k] = (p == outletNew);
    float Lv = Lg[oldi];
    float sS = fmaxf(Sg[oldi], 1e-6f);
    float mnv = fmaxf(mng[oldi], 1e-3f);
    lvk_r[k] = 0.7369656f + 0.5f * LOG2(sS) - LOG2(mnv);  // log2(5/3*sqrt(S)/n)
    lgSL_r[k] = LOG2(sS * Lv);
    L_r[k] = Lv;
    lwc_r[k] = LOG2(wcg[oldi]);
    we_r[k] = weg[oldi];
    ldc_r[k] = LOG2(dcg[oldi]);
    de_r[k] = deg[oldi];
    float q0 = initQ[oldi];
    q1_r[k] = q0;
    q2_r[k] = q0;
    ip_r[k] = 0.f;
    wOff_r[k] = 0;  // byte offset of current win slot
    latcol_r[k] = lat + oldi;   // direct gather (L2-resident, prefetched)
    latN_r[k] = *latcol_r[k];   // t=0 prefetch
  }
  __syncthreads();  // all scratch reads done before pads clobber scratch
  if (tid < WLDS) win_s[tid * SSTR + 4096] = 0.f;  // pad cells
  __syncthreads();

#define BODY(k, tt)                                                             \
  {                                                                             \
    const int p = tid + (k)*1024;                                               \
    const float latv = latN_r[k];                                               \
    int tn = (tt) + 1;                                                          \
    tn = tn < NT ? tn : NT - 1;                                                 \
    latN_r[k] = latcol_r[k][tn << 12];                                          \
    const char* wb = (const char*)win_s + wOff_r[k];                            \
    float v0 = *(const float*)(wb + sc_r[k][0]);                                \
    float v1 = *(const float*)(wb + sc_r[k][1]);                                \
    float v2 = *(const float*)(wb + sc_r[k][2]);                                \
    float v3 = *(const float*)(wb + sc_r[k][3]);                                \
    float ssum = 0.f;                                                           \
    const int sC = (int)((smeta_r[k] >> 20) & 63);                              \
    if (sC) {                                                                   \
      const int sB = (int)(smeta_r[k] & 0xFFFFFu);                              \
      for (int e = 0; e < sC; ++e)                                              \
        ssum += *(const float*)(wb + srem_s[sB + e]);                           \
    }                                                                           \
    float lsum = 0.f;                                                           \
    const int lC = (int)(lmeta_r[k] >> 20);                                     \
    if (lC) {                                                                   \
      const int lB = (int)(lmeta_r[k] & 0xFFFFFu);                              \
      const char* qb = (const char*)Qhist + (((tt) & 31) << 14);                \
      for (int e = 0; e < lC; ++e) lsum += *(const float*)(qb + long_s[lB + e]);\
    }                                                                           \
    float Qref = fmaxf(q1_r[k], 0.1f);                                          \
    float lq = LOG2(Qref);                                                      \
    float lgW = fmaf(we_r[k], lq, lwc_r[k]);                                    \
    float W = EXP2(lgW);                                                        \
    float aD = fmaf(de_r[k], lq, ldc_r[k]);                                     \
    float Dd = EXP2(aD);                                                        \
    float lgR = fmaxf(lgW + aD - LOG2(fmaf(2.f, Dd, W)), LOG2_1E6);             \
    float lgc = fmaf(0.66666667f, lgR, lvk_r[k]);                               \
    float K = fmaxf(L_r[k] * EXP2(-lgc), 360.f);                                \
    float ratio = EXP2(lq - lgW - lgc - lgSL_r[k]);                             \
    float X = fmaxf(fmaf(-0.5f, ratio, 0.5f), 0.f);                             \
    float twoK = K + K;                                                         \
    float twoKX = twoK * X;                                                     \
    float C0 = fmaxf(DTSTEP - twoKX, 0.f);                                      \
    float C1 = DTSTEP + twoKX;                                                  \
    float C2 = fmaxf(twoK - twoKX - DTSTEP, 0.f);                               \
    float inv = RCP(C0 + C1 + C2);                                              \
    float sup = ((v0 + v1) + (v2 + v3)) + (ssum + lsum);                        \
    float Icurr = sup + latv;                                                   \
    float Qout = fmaxf((C0 * Icurr + C1 * ip_r[k] + C2 * q2_r[k]) * inv, 0.f);  \
    *(float*)((char*)win_s + wOff_r[k] + (p << 2)) = Qout;                      \
    if (ls_r[k]) Qhist[(((tt) & 31) << 12) | p] = Qout;                         \
    if (io_r[k]) out[tt] = Qout;                                                \
    ip_r[k] = Icurr;                                                            \
    q2_r[k] = q1_r[k];                                                          \
    q1_r[k] = Qout;                                                             \
    wOff_r[k] =                                                                 \
        (wOff_r[k] == (WLDS - 1) * SSTR * 4) ? 0 : wOff_r[k] + SSTR * 4;        \
  }

  // ramp-up: per-body validity checks
  for (int s = 0; s < nlv - 1; ++s) {
#pragma unroll
    for (int k = 0; k < 4; ++k) {
      int t = s - lev_r[k];
      if ((unsigned)t < (unsigned)NT) BODY(k, t);
    }
    phase_barrier();
  }
  // steady: all rows active, no validity checks
  for (int s = nlv - 1; s < NT; ++s) {
#pragma unroll
    for (int k = 0; k < 4; ++k) {
      int t = s - lev_r[k];
      BODY(k, t);
    }
    phase_barrier();
  }
  // drain
  for (int s = NT; s < NT + nlv - 1; ++s) {
#pragma unroll
    for (int k = 0; k < 4; ++k) {
      int t = s - lev_r[k];
      if ((unsigned)t < (unsigned)NT) BODY(k, t);
    }
    phase_barrier();
  }
}

extern "C" void kernel_launch(void* const* d_in, const int* in_sizes, int n_in,
                              void* d_out, int out_size, void* d_ws, size_t ws_size,
                              hipStream_t stream) {
  const float* lat = (const float*)d_in[0];
  const float* iQ = (const float*)d_in[1];
  const float* Lg = (const float*)d_in[2];
  const float* Sg = (const float*)d_in[3];
  const float* mng = (const float*)d_in[4];
  const float* wcg = (const float*)d_in[5];
  const float* weg = (const float*)d_in[6];
  const float* dcg = (const float*)d_in[7];
  const float* deg = (const float*)d_in[8];
  const int* mask = (const int*)d_in[9];
  float* out = (float*)d_out;

  char* w = (char*)d_ws;
  int* rowBase = (int*)w;                        w += NR * 4;
  int* rowCnt = (int*)w;                         w += NR * 4;
  int* gctr = (int*)w;                           w += 16;
  unsigned short* colsOld = (unsigned short*)w;  w += NNZ_CAP * 2;
  w += 16 - ((size_t)w & 15);
  float* Qhist = (float*)w;                      w += (size_t)DHIST * NR * 4;

  hipMemsetAsync(gctr, 0, 16, stream);
  mc_build<<<NR, 64, 0, stream>>>(mask, rowBase, rowCnt, gctr, colsOld);
  mc_fused<<<1, 1024, 0, stream>>>(lat, iQ, Lg, Sg, mng, wcg, weg, dcg, deg,
                                   rowBase, rowCnt, gctr, colsOld, Qhist, out);
}